// Round 3
// baseline (440.244 us; speedup 1.0000x reference)
//
#include <hip/hip_runtime.h>

typedef unsigned short u16;
typedef __attribute__((ext_vector_type(8))) short short8;
typedef __attribute__((ext_vector_type(4))) float f32x4;

#define D_DIM   1024
#define ROWS    32768   // B*T = 4*8192
#define T_DIM   8192

__device__ __forceinline__ float bf2f(u16 u) {
    union { unsigned int i; float f; } c; c.i = ((unsigned int)u) << 16; return c.f;
}
__device__ __forceinline__ u16 f2bf(float f) {
    union { float f; unsigned int i; } c; c.f = f;
    unsigned int r = c.i + 0x7FFF + ((c.i >> 16) & 1);   // RNE
    return (u16)(r >> 16);
}

#define GLL16(gp, lp) \
    __builtin_amdgcn_global_load_lds((const __attribute__((address_space(1))) void*)(gp), \
                                     (__attribute__((address_space(3))) void*)(lp), 16, 0, 0)

// ---------------- Kernel 0: x fp32 -> xb bf16 ----------------
__global__ void convert_x(const float* __restrict__ x, u16* __restrict__ xb) {
    size_t idx = ((size_t)blockIdx.x * 256 + threadIdx.x) * 8;
    float4 f0 = *reinterpret_cast<const float4*>(x + idx);
    float4 f1 = *reinterpret_cast<const float4*>(x + idx + 4);
    short8 v;
    v[0] = (short)f2bf(f0.x); v[1] = (short)f2bf(f0.y);
    v[2] = (short)f2bf(f0.z); v[3] = (short)f2bf(f0.w);
    v[4] = (short)f2bf(f1.x); v[5] = (short)f2bf(f1.y);
    v[6] = (short)f2bf(f1.z); v[7] = (short)f2bf(f1.w);
    *reinterpret_cast<short8*>(xb + idx) = v;
}

// ---------------- Kernel 1: convert+transpose Wqkv (1024x3072 fp32) -> WT (3072x1024 bf16) ----
__global__ void transpose_w(const float* __restrict__ W, u16* __restrict__ WT) {
    __shared__ u16 tile[32][34];
    int nb = blockIdx.x * 32;
    int kb = blockIdx.y * 32;
    int tx = threadIdx.x;   // 0..31
    int ty = threadIdx.y;   // 0..7
    #pragma unroll
    for (int i = 0; i < 32; i += 8)
        tile[ty + i][tx] = f2bf(W[(size_t)(kb + ty + i) * 3072 + nb + tx]);
    __syncthreads();
    #pragma unroll
    for (int i = 0; i < 32; i += 8)
        WT[(size_t)(nb + ty + i) * D_DIM + kb + tx] = tile[tx][ty + i];
}

// ---------------- Kernel 2: 256x256 tile, 4-slot K=32 ring, register-prefetch pipeline ----
// C[row, col] = sum_k xb[row,k] * WT[col,k] + bqkv[col]
// ONE phase per slot: { ds_read frags for slot s+1 (12 b128, into other reg set);
//   GLL for slot s+3 (4); 32 MFMA on slot-s frags (lgkmcnt(12) auto -> prefetch stays
//   in flight under MFMA); vmcnt(4) certifies slot s+2; barrier }.
// LDS reads now OVERLAP the MFMA cluster (the round-2 serialization was the stall).
// Residency proof: close of slot s-1 ran vmcnt(4) -> drains GLLs of s+1 (only s+2's 4
// newer remain) -> barrier -> s+1 resident for all waves before its reads issue in slot s.
// Write-after-read: reads of ring r (slot s) drain before MFMA_s < barrier_s < GLL to
// ring r for slot s+4 (issued during s+1). One barrier per slot.
// Swizzle: 16B-group g' = g ^ ((row>>1)&3): within a 16-lane phase group a fragment
// ds_read_b128 hits 8 distinct bank-starts x 2 lanes (2-way = free, m136).

#define SLOT(RN, RS, CA, CB, NA, NB, STG, PF, VM) do {                            \
    if (PF) {                                                                     \
        _Pragma("unroll")                                                         \
        for (int mi = 0; mi < 8; ++mi)                                            \
            NA[mi] = *reinterpret_cast<const short8*>(&a_sh[RN][aRd + mi * 512]); \
        _Pragma("unroll")                                                         \
        for (int nt = 0; nt < 4; ++nt)                                            \
            NB[nt] = *reinterpret_cast<const short8*>(&b_sh[RN][bRd + nt * 512]); \
    }                                                                             \
    if (STG) {                                                                    \
        GLL16(aPtr0, &a_sh[RS][aDst0]); GLL16(aPtr1, &a_sh[RS][aDst1]);           \
        GLL16(bPtr0, &b_sh[RS][aDst0]); GLL16(bPtr1, &b_sh[RS][aDst1]);           \
        aPtr0 += 32; aPtr1 += 32; bPtr0 += 32; bPtr1 += 32;                       \
    }                                                                             \
    __builtin_amdgcn_sched_barrier(0);                                            \
    __builtin_amdgcn_s_setprio(1);                                                \
    _Pragma("unroll")                                                             \
    for (int mi = 0; mi < 8; ++mi)                                                \
        _Pragma("unroll")                                                         \
        for (int nt = 0; nt < 4; ++nt)                                            \
            acc[mi][nt] = __builtin_amdgcn_mfma_f32_16x16x32_bf16(                \
                CA[mi], CB[nt], acc[mi][nt], 0, 0, 0);                            \
    __builtin_amdgcn_s_setprio(0);                                                \
    if ((VM) == 4)      asm volatile("s_waitcnt vmcnt(4)" ::: "memory");          \
    else if ((VM) == 0) asm volatile("s_waitcnt vmcnt(0)" ::: "memory");          \
    __builtin_amdgcn_s_barrier();                                                 \
    __builtin_amdgcn_sched_barrier(0);                                            \
} while (0)

__global__ __launch_bounds__(512, 2)
void gemm_k(const u16* __restrict__ xb, const u16* __restrict__ WT,
            const float* __restrict__ bqkv,
            u16* __restrict__ qb, u16* __restrict__ kvb,
            float* __restrict__ qssq, float* __restrict__ kssq)
{
    // 4-slot ring: each slot 256 rows x 32 k (u16) = 16 KB per operand; 128 KiB total
    __shared__ __align__(16) u16 a_sh[4][8192];
    __shared__ __align__(16) u16 b_sh[4][8192];

    const int tid  = threadIdx.x;
    const int lane = tid & 63;
    const int w    = tid >> 6;      // wave 0..7
    const int l15  = lane & 15;
    const int quad = lane >> 4;     // 0..3
    const int wm   = w >> 2;        // 0..1  (M half)
    const int wn   = w & 3;         // 0..3  (N quarter)

    // bijective XCD swizzle: 1536 blocks, 192 contiguous (bx,by) per XCD
    const int flat = blockIdx.x;
    const int swz  = (flat & 7) * 192 + (flat >> 3);
    const int bx   = swz & 127;     // 0..127 (M)
    const int by   = swz >> 7;      // 0..11  (N)
    const int r0   = bx * 256;
    const int c0   = by * 256;

    // ---- staging addresses ----
    // thread stages 16B groups sidx = w*128 + i*64 + lane (i=0,1) per operand per slot.
    // sidx -> row = sidx>>2, g' = sidx&3; source k-group gsrc = g' ^ ((row>>1)&3).
    const int row0 = w * 32 + (lane >> 2);
    const int gsrc = (lane & 3) ^ ((lane >> 3) & 3);   // same for i=0,1 (rows differ by 16)
    const u16* aPtr0 = xb + (size_t)(r0 + row0) * D_DIM + gsrc * 8;
    const u16* aPtr1 = xb + (size_t)(r0 + row0 + 16) * D_DIM + gsrc * 8;
    const u16* bPtr0 = WT + (size_t)(c0 + row0) * D_DIM + gsrc * 8;
    const u16* bPtr1 = WT + (size_t)(c0 + row0 + 16) * D_DIM + gsrc * 8;
    const int aDst0 = w * 1024;          // wave-uniform linear LDS dest (u16 idx)
    const int aDst1 = w * 1024 + 512;

    // ---- fragment read offsets (u16 index within a slot) ----
    // row = base + l15 (base mult of 16) -> (row>>1)&3 == (l15>>1)&3
    const int gq  = (quad ^ ((l15 >> 1) & 3)) * 8;
    const int aRd = (wm * 128 + l15) * 32 + gq;      // + mi*512, mi=0..7
    const int bRd = (wn * 64 + l15) * 32 + gq;       // + nt*512, nt=0..3

    f32x4 acc[8][4];
    #pragma unroll
    for (int mi = 0; mi < 8; ++mi)
        #pragma unroll
        for (int nt = 0; nt < 4; ++nt) acc[mi][nt] = (f32x4)(0.0f);

    short8 cA0[8], cB0[4], cA1[8], cB1[4];

    // ---- prologue: stage slots 0,1,2 ----
    GLL16(aPtr0, &a_sh[0][aDst0]); GLL16(aPtr1, &a_sh[0][aDst1]);
    GLL16(bPtr0, &b_sh[0][aDst0]); GLL16(bPtr1, &b_sh[0][aDst1]);
    aPtr0 += 32; aPtr1 += 32; bPtr0 += 32; bPtr1 += 32;
    GLL16(aPtr0, &a_sh[1][aDst0]); GLL16(aPtr1, &a_sh[1][aDst1]);
    GLL16(bPtr0, &b_sh[1][aDst0]); GLL16(bPtr1, &b_sh[1][aDst1]);
    aPtr0 += 32; aPtr1 += 32; bPtr0 += 32; bPtr1 += 32;
    GLL16(aPtr0, &a_sh[2][aDst0]); GLL16(aPtr1, &a_sh[2][aDst1]);
    GLL16(bPtr0, &b_sh[2][aDst0]); GLL16(bPtr1, &b_sh[2][aDst1]);
    aPtr0 += 32; aPtr1 += 32; bPtr0 += 32; bPtr1 += 32;
    asm volatile("s_waitcnt vmcnt(4)" ::: "memory");   // slots 0 AND 1 resident (own loads)
    __builtin_amdgcn_s_barrier();                      // ... for all waves
    __builtin_amdgcn_sched_barrier(0);

    // initial fragment reads for slot 0 (ring 0) into set 0
    #pragma unroll
    for (int mi = 0; mi < 8; ++mi)
        cA0[mi] = *reinterpret_cast<const short8*>(&a_sh[0][aRd + mi * 512]);
    #pragma unroll
    for (int nt = 0; nt < 4; ++nt)
        cB0[nt] = *reinterpret_cast<const short8*>(&b_sh[0][bRd + nt * 512]);

    // ---- main loop: slots 0..27 ----
    #pragma unroll 1
    for (int it = 0; it < 7; ++it) {
        SLOT(1, 3, cA0, cB0, cA1, cB1, 1, 1, 4);   // slot 4it+0: pf ring1, stg ring3
        SLOT(2, 0, cA1, cB1, cA0, cB0, 1, 1, 4);   // slot 4it+1
        SLOT(3, 1, cA0, cB0, cA1, cB1, 1, 1, 4);   // slot 4it+2
        SLOT(0, 2, cA1, cB1, cA0, cB0, 1, 1, 4);   // slot 4it+3
    }
    // ---- tail: slots 28..31 ----
    SLOT(1, 3, cA0, cB0, cA1, cB1, 1, 1, 4);       // 28: stage slot 31
    SLOT(2, 0, cA1, cB1, cA0, cB0, 0, 1, 0);       // 29: vmcnt(0) certifies slot 31
    SLOT(3, 0, cA0, cB0, cA1, cB1, 0, 1, -1);      // 30: pf slot 31 (ring 3)
    SLOT(0, 0, cA1, cB1, cA0, cB0, 0, 0, -1);      // 31

    // ---- epilogue: bias ----
    float bcol[4];
    #pragma unroll
    for (int nt = 0; nt < 4; ++nt)
        bcol[nt] = bqkv[c0 + wn * 64 + nt * 16 + l15];
    #pragma unroll
    for (int mi = 0; mi < 8; ++mi)
        #pragma unroll
        for (int nt = 0; nt < 4; ++nt)
            #pragma unroll
            for (int rg = 0; rg < 4; ++rg) acc[mi][nt][rg] += bcol[nt];

    // ---- row sum-of-squares (q and k blocks only) ----
    if (by < 8) {
        float* ssq = (by < 4) ? qssq : kssq;
        #pragma unroll
        for (int mi = 0; mi < 8; ++mi)
            #pragma unroll
            for (int rg = 0; rg < 4; ++rg) {
                float s = acc[mi][0][rg] * acc[mi][0][rg]
                        + acc[mi][1][rg] * acc[mi][1][rg]
                        + acc[mi][2][rg] * acc[mi][2][rg]
                        + acc[mi][3][rg] * acc[mi][3][rg];
                #pragma unroll
                for (int m = 1; m < 16; m <<= 1) s += __shfl_xor(s, m, 16);
                if (l15 == 0)
                    atomicAdd(&ssq[r0 + wm * 128 + mi * 16 + quad * 4 + rg], s);
            }
    }

    // ---- store bf16 ----
    u16* dst;
    int ldc, cb;
    if (by < 4) { dst = qb;  ldc = 1024; cb = c0; }
    else        { dst = kvb; ldc = 2048; cb = c0 - 1024; }
    #pragma unroll
    for (int mi = 0; mi < 8; ++mi)
        #pragma unroll
        for (int nt = 0; nt < 4; ++nt) {
            int col = cb + wn * 64 + nt * 16 + l15;
            #pragma unroll
            for (int rg = 0; rg < 4; ++rg) {
                int row = r0 + wm * 128 + mi * 16 + quad * 4 + rg;
                dst[(size_t)row * ldc + col] = f2bf(acc[mi][nt][rg]);
            }
        }
}

// ---------------- Kernel 3: kv[b,d] = sum_t k*v*rsqrt(kssq) ----------------
__global__ void kv_reduce(const u16* __restrict__ kvb, const float* __restrict__ kssq,
                          float* __restrict__ kv)
{
    int d  = threadIdx.x * 8;                  // 128 threads cover 1024 d
    int b  = blockIdx.y;                       // 0..3
    int t0 = blockIdx.x * 64;                  // 128 t-chunks of 64 rows
    float a[8];
    #pragma unroll
    for (int e = 0; e < 8; ++e) a[e] = 0.0f;
    for (int r = 0; r < 64; ++r) {
        int row = b * T_DIM + t0 + r;
        float kin = rsqrtf(kssq[row]);
        short8 k8 = *reinterpret_cast<const short8*>(kvb + (size_t)row * 2048 + d);
        short8 v8 = *reinterpret_cast<const short8*>(kvb + (size_t)row * 2048 + 1024 + d);
        #pragma unroll
        for (int e = 0; e < 8; ++e)
            a[e] += bf2f((u16)k8[e]) * bf2f((u16)v8[e]) * kin;
    }
    #pragma unroll
    for (int e = 0; e < 8; ++e)
        atomicAdd(&kv[b * D_DIM + d + e], a[e]);
}

// ---------------- Kernel 4: out = q*rsqrt(qssq)*kv*scale + bias (fp32) ----------------
__global__ void finalize(const u16* __restrict__ qb, const float* __restrict__ qssq,
                         const float* __restrict__ kv, const float* __restrict__ scale,
                         const float* __restrict__ bias, float* __restrict__ out)
{
    size_t idx = (size_t)blockIdx.x * 256 + threadIdx.x;   // vec8 index
    int row = (int)(idx >> 7);
    int dv  = ((int)idx & 127) * 8;
    int b   = row >> 13;
    float qi = rsqrtf(qssq[row]);
    short8 qv = *reinterpret_cast<const short8*>(qb + (size_t)row * D_DIM + dv);
    const float* kvp = kv + b * D_DIM + dv;
    const float* sp  = scale + dv;
    const float* bp  = bias + dv;
    float4 o0, o1;
    o0.x = bf2f((u16)qv[0]) * qi * kvp[0] * sp[0] + bp[0];
    o0.y = bf2f((u16)qv[1]) * qi * kvp[1] * sp[1] + bp[1];
    o0.z = bf2f((u16)qv[2]) * qi * kvp[2] * sp[2] + bp[2];
    o0.w = bf2f((u16)qv[3]) * qi * kvp[3] * sp[3] + bp[3];
    o1.x = bf2f((u16)qv[4]) * qi * kvp[4] * sp[4] + bp[4];
    o1.y = bf2f((u16)qv[5]) * qi * kvp[5] * sp[5] + bp[5];
    o1.z = bf2f((u16)qv[6]) * qi * kvp[6] * sp[6] + bp[6];
    o1.w = bf2f((u16)qv[7]) * qi * kvp[7] * sp[7] + bp[7];
    float* op = out + (size_t)row * D_DIM + dv;
    *reinterpret_cast<float4*>(op)     = o0;
    *reinterpret_cast<float4*>(op + 4) = o1;
}

extern "C" void kernel_launch(void* const* d_in, const int* in_sizes, int n_in,
                              void* d_out, int out_size, void* d_ws, size_t ws_size,
                              hipStream_t stream) {
    const float* x     = (const float*)d_in[0];
    const float* W     = (const float*)d_in[1];
    const float* bqkv  = (const float*)d_in[2];
    const float* scale = (const float*)d_in[3];
    const float* bias  = (const float*)d_in[4];
    float* out = (float*)d_out;

    // d_out doubles as scratch until finalize: xb (64 MB) + WT (6 MB) < 128 MB
    u16* xb = (u16*)d_out;
    u16* WT = (u16*)((char*)d_out + 67108864);

    char* ws = (char*)d_ws;
    u16*   qb   = (u16*)ws;                         //  67,108,864 B
    u16*   kvb  = (u16*)(ws + 67108864);            // 134,217,728 B
    float* qssq = (float*)(ws + 201326592);         //     131,072 B
    float* kssq = (float*)(ws + 201457664);         //     131,072 B
    float* kv   = (float*)(ws + 201588736);         //      16,384 B

    convert_x  <<<dim3(ROWS * D_DIM / 8 / 256), dim3(256), 0, stream>>>(x, xb);
    transpose_w<<<dim3(96, 32), dim3(32, 8), 0, stream>>>(W, WT);
    hipMemsetAsync(qssq, 0, 131072 + 131072 + 16384, stream);
    gemm_k     <<<dim3(1536), dim3(512), 0, stream>>>(xb, WT, bqkv, qb, kvb, qssq, kssq);
    kv_reduce  <<<dim3(T_DIM / 64, 4), dim3(128), 0, stream>>>(kvb, kssq, kv);
    finalize   <<<dim3(ROWS * (D_DIM / 8) / 256), dim3(256), 0, stream>>>(qb, qssq, kv, scale, bias, out);
}

// Round 4
// 387.899 us; speedup vs baseline: 1.1349x; 1.1349x over previous
//
#include <hip/hip_runtime.h>

typedef unsigned short u16;
typedef __attribute__((ext_vector_type(8))) short short8;
typedef __attribute__((ext_vector_type(4))) float f32x4;

#define D_DIM   1024
#define ROWS    32768   // B*T = 4*8192
#define T_DIM   8192

__device__ __forceinline__ float bf2f(u16 u) {
    union { unsigned int i; float f; } c; c.i = ((unsigned int)u) << 16; return c.f;
}
__device__ __forceinline__ u16 f2bf(float f) {
    union { float f; unsigned int i; } c; c.f = f;
    unsigned int r = c.i + 0x7FFF + ((c.i >> 16) & 1);   // RNE
    return (u16)(r >> 16);
}

#define GLL16(gp, lp) \
    __builtin_amdgcn_global_load_lds((const __attribute__((address_space(1))) void*)(gp), \
                                     (__attribute__((address_space(3))) void*)(lp), 16, 0, 0)

// ---------------- Kernel 0: x fp32 -> xb bf16 ----------------
__global__ void convert_x(const float* __restrict__ x, u16* __restrict__ xb) {
    size_t idx = ((size_t)blockIdx.x * 256 + threadIdx.x) * 8;
    float4 f0 = *reinterpret_cast<const float4*>(x + idx);
    float4 f1 = *reinterpret_cast<const float4*>(x + idx + 4);
    short8 v;
    v[0] = (short)f2bf(f0.x); v[1] = (short)f2bf(f0.y);
    v[2] = (short)f2bf(f0.z); v[3] = (short)f2bf(f0.w);
    v[4] = (short)f2bf(f1.x); v[5] = (short)f2bf(f1.y);
    v[6] = (short)f2bf(f1.z); v[7] = (short)f2bf(f1.w);
    *reinterpret_cast<short8*>(xb + idx) = v;
}

// ---------------- Kernel 1: convert+transpose Wqkv (1024x3072 fp32) -> WT (3072x1024 bf16) ----
__global__ void transpose_w(const float* __restrict__ W, u16* __restrict__ WT) {
    __shared__ u16 tile[32][34];
    int nb = blockIdx.x * 32;
    int kb = blockIdx.y * 32;
    int tx = threadIdx.x;   // 0..31
    int ty = threadIdx.y;   // 0..7
    #pragma unroll
    for (int i = 0; i < 32; i += 8)
        tile[ty + i][tx] = f2bf(W[(size_t)(kb + ty + i) * 3072 + nb + tx]);
    __syncthreads();
    #pragma unroll
    for (int i = 0; i < 32; i += 8)
        WT[(size_t)(nb + ty + i) * D_DIM + kb + tx] = tile[tx][ty + i];
}

// ---------------- Kernel 2: 256x256 tile, 4-slot K=32 ring, compiler-scheduled slots ----
// C[row, col] = sum_k xb[row,k] * WT[col,k] + bqkv[col]
// Ring of 4 slots (A 16KB + B 16KB each) = 128 KiB, staged 3 slots ahead.
// ONE slot = { 12 ds_read_b128 (B first: first MFMA needs only 5 reads), 4 GLL for
//   slot s+3, 32 MFMA, sched_barrier(0), counted vmcnt, s_barrier }.
// Design notes (r3 post-mortem): NO register double-buffer (r3 spilled: +79MB scratch
// writes), NO per-cluster sched_barrier/setprio (m141: pinning defeats the compiler's
// fine lgkmcnt interleave -- the compiler's native ds_read/MFMA scheduling plus 2
// de-phased waves/SIMD provide the overlap). One barrier per slot.
// Residency: GLLs for slot s issued during slot s-3; end-of-slot-(s-1) vmcnt(8)
// leaves only (->s+1),(->s+2) in flight => slot s resident; barrier certifies
// cross-wave. WAR: GLL in slot s writes ring[(s+3)&3] = ring[(s-1)&3]; its readers
// finished before their MFMAs, which precede barrier(s-1) < GLL issue (slot s).
// vmcnt never 0 until the drain tail (T4).
// Swizzle (r3, measured 0 conflicts): 16B-group g' = g ^ ((row>>1)&3).

#define SLOT(RING, SRING, STG, VM) do {                                           \
    short8 bF[4], aF[8];                                                          \
    _Pragma("unroll")                                                             \
    for (int nt = 0; nt < 4; ++nt)                                                \
        bF[nt] = *reinterpret_cast<const short8*>(&b_sh[RING][bRd + nt * 512]);   \
    _Pragma("unroll")                                                             \
    for (int mi = 0; mi < 8; ++mi)                                                \
        aF[mi] = *reinterpret_cast<const short8*>(&a_sh[RING][aRd + mi * 512]);   \
    if (STG) {                                                                    \
        GLL16(aPtr0, &a_sh[SRING][aDst0]); GLL16(aPtr1, &a_sh[SRING][aDst1]);     \
        GLL16(bPtr0, &b_sh[SRING][aDst0]); GLL16(bPtr1, &b_sh[SRING][aDst1]);     \
        aPtr0 += 32; aPtr1 += 32; bPtr0 += 32; bPtr1 += 32;                       \
    }                                                                             \
    _Pragma("unroll")                                                             \
    for (int mi = 0; mi < 8; ++mi)                                                \
        _Pragma("unroll")                                                         \
        for (int nt = 0; nt < 4; ++nt)                                            \
            acc[mi][nt] = __builtin_amdgcn_mfma_f32_16x16x32_bf16(                \
                aF[mi], bF[nt], acc[mi][nt], 0, 0, 0);                            \
    __builtin_amdgcn_sched_barrier(0);                                            \
    if ((VM) == 8)      asm volatile("s_waitcnt vmcnt(8)" ::: "memory");          \
    else if ((VM) == 4) asm volatile("s_waitcnt vmcnt(4)" ::: "memory");          \
    else if ((VM) == 0) asm volatile("s_waitcnt vmcnt(0)" ::: "memory");          \
    __builtin_amdgcn_s_barrier();                                                 \
} while (0)

__global__ __launch_bounds__(512, 1)
void gemm_k(const u16* __restrict__ xb, const u16* __restrict__ WT,
            const float* __restrict__ bqkv,
            u16* __restrict__ qb, u16* __restrict__ kvb,
            float* __restrict__ qssq, float* __restrict__ kssq)
{
    // 4-slot ring: each slot 256 rows x 32 k (u16) = 16 KB per operand; 128 KiB total
    __shared__ __align__(16) u16 a_sh[4][8192];
    __shared__ __align__(16) u16 b_sh[4][8192];

    const int tid  = threadIdx.x;
    const int lane = tid & 63;
    const int w    = tid >> 6;      // wave 0..7
    const int l15  = lane & 15;
    const int quad = lane >> 4;     // 0..3
    const int wm   = w >> 2;        // 0..1  (M half)
    const int wn   = w & 3;         // 0..3  (N quarter)

    // bijective XCD swizzle: 1536 blocks, 192 contiguous (bx,by) per XCD
    const int flat = blockIdx.x;
    const int swz  = (flat & 7) * 192 + (flat >> 3);
    const int bx   = swz & 127;     // 0..127 (M)
    const int by   = swz >> 7;      // 0..11  (N)
    const int r0   = bx * 256;
    const int c0   = by * 256;

    // ---- staging addresses ----
    // thread stages 16B groups sidx = w*128 + i*64 + lane (i=0,1) per operand per slot.
    // sidx -> row = sidx>>2, g' = sidx&3; source k-group gsrc = g' ^ ((row>>1)&3).
    const int row0 = w * 32 + (lane >> 2);
    const int gsrc = (lane & 3) ^ ((lane >> 3) & 3);   // same for i=0,1 (rows differ by 16)
    const u16* aPtr0 = xb + (size_t)(r0 + row0) * D_DIM + gsrc * 8;
    const u16* aPtr1 = xb + (size_t)(r0 + row0 + 16) * D_DIM + gsrc * 8;
    const u16* bPtr0 = WT + (size_t)(c0 + row0) * D_DIM + gsrc * 8;
    const u16* bPtr1 = WT + (size_t)(c0 + row0 + 16) * D_DIM + gsrc * 8;
    const int aDst0 = w * 1024;          // wave-uniform linear LDS dest (u16 idx)
    const int aDst1 = w * 1024 + 512;

    // ---- fragment read offsets (u16 index within a slot) ----
    // row = base + l15 (base mult of 16) -> (row>>1)&3 == (l15>>1)&3
    const int gq  = (quad ^ ((l15 >> 1) & 3)) * 8;
    const int aRd = (wm * 128 + l15) * 32 + gq;      // + mi*512, mi=0..7
    const int bRd = (wn * 64 + l15) * 32 + gq;       // + nt*512, nt=0..3

    f32x4 acc[8][4];
    #pragma unroll
    for (int mi = 0; mi < 8; ++mi)
        #pragma unroll
        for (int nt = 0; nt < 4; ++nt) acc[mi][nt] = (f32x4)(0.0f);

    // ---- prologue: stage slots 0,1,2 ----
    GLL16(aPtr0, &a_sh[0][aDst0]); GLL16(aPtr1, &a_sh[0][aDst1]);
    GLL16(bPtr0, &b_sh[0][aDst0]); GLL16(bPtr1, &b_sh[0][aDst1]);
    aPtr0 += 32; aPtr1 += 32; bPtr0 += 32; bPtr1 += 32;
    GLL16(aPtr0, &a_sh[1][aDst0]); GLL16(aPtr1, &a_sh[1][aDst1]);
    GLL16(bPtr0, &b_sh[1][aDst0]); GLL16(bPtr1, &b_sh[1][aDst1]);
    aPtr0 += 32; aPtr1 += 32; bPtr0 += 32; bPtr1 += 32;
    GLL16(aPtr0, &a_sh[2][aDst0]); GLL16(aPtr1, &a_sh[2][aDst1]);
    GLL16(bPtr0, &b_sh[2][aDst0]); GLL16(bPtr1, &b_sh[2][aDst1]);
    aPtr0 += 32; aPtr1 += 32; bPtr0 += 32; bPtr1 += 32;
    asm volatile("s_waitcnt vmcnt(8)" ::: "memory");   // slot 0 resident (own loads)
    __builtin_amdgcn_s_barrier();                      // ... for all waves

    // ---- main loop: slots 0..27; slot s reads ring s&3, stages ring (s+3)&3 ----
    #pragma unroll 1
    for (int it = 0; it < 7; ++it) {
        SLOT(0, 3, 1, 8);
        SLOT(1, 0, 1, 8);
        SLOT(2, 1, 1, 8);
        SLOT(3, 2, 1, 8);
    }
    // ---- tail: slots 28..31 ----
    SLOT(0, 3, 1, 8);    // 28: stages slot 31; end-wait certifies slot 29
    SLOT(1, 0, 0, 4);    // 29: end-wait certifies slot 30
    SLOT(2, 0, 0, 0);    // 30: end-wait certifies slot 31
    SLOT(3, 0, 0, -1);   // 31

    // ---- epilogue: bias ----
    float bcol[4];
    #pragma unroll
    for (int nt = 0; nt < 4; ++nt)
        bcol[nt] = bqkv[c0 + wn * 64 + nt * 16 + l15];
    #pragma unroll
    for (int mi = 0; mi < 8; ++mi)
        #pragma unroll
        for (int nt = 0; nt < 4; ++nt)
            #pragma unroll
            for (int rg = 0; rg < 4; ++rg) acc[mi][nt][rg] += bcol[nt];

    // ---- row sum-of-squares (q and k blocks only) ----
    if (by < 8) {
        float* ssq = (by < 4) ? qssq : kssq;
        #pragma unroll
        for (int mi = 0; mi < 8; ++mi)
            #pragma unroll
            for (int rg = 0; rg < 4; ++rg) {
                float s = acc[mi][0][rg] * acc[mi][0][rg]
                        + acc[mi][1][rg] * acc[mi][1][rg]
                        + acc[mi][2][rg] * acc[mi][2][rg]
                        + acc[mi][3][rg] * acc[mi][3][rg];
                #pragma unroll
                for (int m = 1; m < 16; m <<= 1) s += __shfl_xor(s, m, 16);
                if (l15 == 0)
                    atomicAdd(&ssq[r0 + wm * 128 + mi * 16 + quad * 4 + rg], s);
            }
    }

    // ---- store bf16 ----
    u16* dst;
    int ldc, cb;
    if (by < 4) { dst = qb;  ldc = 1024; cb = c0; }
    else        { dst = kvb; ldc = 2048; cb = c0 - 1024; }
    #pragma unroll
    for (int mi = 0; mi < 8; ++mi)
        #pragma unroll
        for (int nt = 0; nt < 4; ++nt) {
            int col = cb + wn * 64 + nt * 16 + l15;
            #pragma unroll
            for (int rg = 0; rg < 4; ++rg) {
                int row = r0 + wm * 128 + mi * 16 + quad * 4 + rg;
                dst[(size_t)row * ldc + col] = f2bf(acc[mi][nt][rg]);
            }
        }
}

// ---------------- Kernel 3: kv[b,d] = sum_t k*v*rsqrt(kssq) ----------------
__global__ void kv_reduce(const u16* __restrict__ kvb, const float* __restrict__ kssq,
                          float* __restrict__ kv)
{
    int d  = threadIdx.x * 8;                  // 128 threads cover 1024 d
    int b  = blockIdx.y;                       // 0..3
    int t0 = blockIdx.x * 64;                  // 128 t-chunks of 64 rows
    float a[8];
    #pragma unroll
    for (int e = 0; e < 8; ++e) a[e] = 0.0f;
    for (int r = 0; r < 64; ++r) {
        int row = b * T_DIM + t0 + r;
        float kin = rsqrtf(kssq[row]);
        short8 k8 = *reinterpret_cast<const short8*>(kvb + (size_t)row * 2048 + d);
        short8 v8 = *reinterpret_cast<const short8*>(kvb + (size_t)row * 2048 + 1024 + d);
        #pragma unroll
        for (int e = 0; e < 8; ++e)
            a[e] += bf2f((u16)k8[e]) * bf2f((u16)v8[e]) * kin;
    }
    #pragma unroll
    for (int e = 0; e < 8; ++e)
        atomicAdd(&kv[b * D_DIM + d + e], a[e]);
}

// ---------------- Kernel 4: out = q*rsqrt(qssq)*kv*scale + bias (fp32) ----------------
__global__ void finalize(const u16* __restrict__ qb, const float* __restrict__ qssq,
                         const float* __restrict__ kv, const float* __restrict__ scale,
                         const float* __restrict__ bias, float* __restrict__ out)
{
    size_t idx = (size_t)blockIdx.x * 256 + threadIdx.x;   // vec8 index
    int row = (int)(idx >> 7);
    int dv  = ((int)idx & 127) * 8;
    int b   = row >> 13;
    float qi = rsqrtf(qssq[row]);
    short8 qv = *reinterpret_cast<const short8*>(qb + (size_t)row * D_DIM + dv);
    const float* kvp = kv + b * D_DIM + dv;
    const float* sp  = scale + dv;
    const float* bp  = bias + dv;
    float4 o0, o1;
    o0.x = bf2f((u16)qv[0]) * qi * kvp[0] * sp[0] + bp[0];
    o0.y = bf2f((u16)qv[1]) * qi * kvp[1] * sp[1] + bp[1];
    o0.z = bf2f((u16)qv[2]) * qi * kvp[2] * sp[2] + bp[2];
    o0.w = bf2f((u16)qv[3]) * qi * kvp[3] * sp[3] + bp[3];
    o1.x = bf2f((u16)qv[4]) * qi * kvp[4] * sp[4] + bp[4];
    o1.y = bf2f((u16)qv[5]) * qi * kvp[5] * sp[5] + bp[5];
    o1.z = bf2f((u16)qv[6]) * qi * kvp[6] * sp[6] + bp[6];
    o1.w = bf2f((u16)qv[7]) * qi * kvp[7] * sp[7] + bp[7];
    float* op = out + (size_t)row * D_DIM + dv;
    *reinterpret_cast<float4*>(op)     = o0;
    *reinterpret_cast<float4*>(op + 4) = o1;
}

extern "C" void kernel_launch(void* const* d_in, const int* in_sizes, int n_in,
                              void* d_out, int out_size, void* d_ws, size_t ws_size,
                              hipStream_t stream) {
    const float* x     = (const float*)d_in[0];
    const float* W     = (const float*)d_in[1];
    const float* bqkv  = (const float*)d_in[2];
    const float* scale = (const float*)d_in[3];
    const float* bias  = (const float*)d_in[4];
    float* out = (float*)d_out;

    // d_out doubles as scratch until finalize: xb (64 MB) + WT (6 MB) < 128 MB
    u16* xb = (u16*)d_out;
    u16* WT = (u16*)((char*)d_out + 67108864);

    char* ws = (char*)d_ws;
    u16*   qb   = (u16*)ws;                         //  67,108,864 B
    u16*   kvb  = (u16*)(ws + 67108864);            // 134,217,728 B
    float* qssq = (float*)(ws + 201326592);         //     131,072 B
    float* kssq = (float*)(ws + 201457664);         //     131,072 B
    float* kv   = (float*)(ws + 201588736);         //      16,384 B

    convert_x  <<<dim3(ROWS * D_DIM / 8 / 256), dim3(256), 0, stream>>>(x, xb);
    transpose_w<<<dim3(96, 32), dim3(32, 8), 0, stream>>>(W, WT);
    hipMemsetAsync(qssq, 0, 131072 + 131072 + 16384, stream);
    gemm_k     <<<dim3(1536), dim3(512), 0, stream>>>(xb, WT, bqkv, qb, kvb, qssq, kssq);
    kv_reduce  <<<dim3(T_DIM / 64, 4), dim3(128), 0, stream>>>(kvb, kssq, kv);
    finalize   <<<dim3(ROWS * (D_DIM / 8) / 256), dim3(256), 0, stream>>>(qb, qssq, kv, scale, bias, out);
}